// Round 1
// baseline (25.879 us; speedup 1.0000x reference)
//
#include <hip/hip_runtime.h>
#include <math.h>

#define NFEAT 22
#define ROWS_PER_THREAD 4
#define BLOCK 256

// Reference quirk replicated exactly: start_i is NEVER incremented in the
// Python reference, so every node i computes relu(x[:, 0:fn_i] @ kernels[off_i:off_i+fn_i] + b_i).
// Only x columns 0..12 are ever read.

__global__ __launch_bounds__(BLOCK) void hnn_fused_kernel(
    const float* __restrict__ x,
    const float* __restrict__ kernels,
    const float* __restrict__ biases,
    const float* __restrict__ final_kernel,
    const float* __restrict__ final_bias,
    float* __restrict__ out,
    int batch)
{
    constexpr int FN[NFEAT] = {10,13,13,7,3,6,3,13,5,4,6,4,5,4,4,5,4,3,3,7,3,3};

    const int base = blockIdx.x * (BLOCK * ROWS_PER_THREAD) + threadIdx.x;

    #pragma unroll
    for (int r = 0; r < ROWS_PER_THREAD; ++r) {
        const int row = base + r * BLOCK;
        if (row >= batch) continue;

        const size_t rb = (size_t)row * 128;
        const float4* xr = reinterpret_cast<const float4*>(x + rb);

        // Load the 13 live columns: 3 x float4 (floats 0..11) + 1 scalar (float 12).
        float4 a = xr[0];
        float4 b = xr[1];
        float4 c = xr[2];
        float xv[13] = {a.x, a.y, a.z, a.w,
                        b.x, b.y, b.z, b.w,
                        c.x, c.y, c.z, c.w,
                        x[rb + 12]};

        float z = final_bias[0];
        int off = 0;
        #pragma unroll
        for (int i = 0; i < NFEAT; ++i) {
            float acc = biases[i];
            #pragma unroll
            for (int j = 0; j < FN[i]; ++j) {
                acc = fmaf(xv[j], kernels[off + j], acc);   // compile-time offsets -> scalar loads
            }
            off += FN[i];
            z = fmaf(fmaxf(acc, 0.0f), final_kernel[i], z);
        }

        // sigmoid
        out[row] = 1.0f / (1.0f + __expf(-z));
    }
}

extern "C" void kernel_launch(void* const* d_in, const int* in_sizes, int n_in,
                              void* d_out, int out_size, void* d_ws, size_t ws_size,
                              hipStream_t stream)
{
    const float* x            = (const float*)d_in[0];
    const float* kernels      = (const float*)d_in[1];
    const float* biases       = (const float*)d_in[2];
    const float* final_kernel = (const float*)d_in[3];
    const float* final_bias   = (const float*)d_in[4];
    float* out = (float*)d_out;

    const int batch = out_size;  // 1048576
    const int rows_per_block = BLOCK * ROWS_PER_THREAD;
    const int grid = (batch + rows_per_block - 1) / rows_per_block;

    hnn_fused_kernel<<<grid, BLOCK, 0, stream>>>(
        x, kernels, biases, final_kernel, final_bias, out, batch);
}